// Round 13
// baseline (283.746 us; speedup 1.0000x reference)
//
#include <hip/hip_runtime.h>
#include <hip/hip_bf16.h>

#define NCH      256
#define NNB      262144
#define BN       64
#define NTILES   (NNB / BN)   // 4096
#define NB       512          // K1 grid: 2 blocks per CU
#define ITPB     (NTILES / NB) // 8 tiles per block
#define NENT     (NCH * 6)
#define NTHREADS 256

typedef __bf16        bf16x8 __attribute__((ext_vector_type(8)));
typedef float         f32x4  __attribute__((ext_vector_type(4)));
typedef unsigned int  u32x4  __attribute__((ext_vector_type(4)));
typedef unsigned int  u32x2  __attribute__((ext_vector_type(2)));
typedef short         v4s    __attribute__((ext_vector_type(4)));

union FragU  { u32x4 u; bf16x8 b; };
union Frag2U { u32x2 u; v4s    s; };

__device__ __forceinline__ unsigned pk2(float lo, float hi) {
    union { __hip_bfloat162 h2; unsigned u; } cv;
    cv.h2 = __float22bfloat162_rn(make_float2(lo, hi));
    return cv.u;
}

__device__ __forceinline__ const float* uni_ptr(const float* p) {
    unsigned long long u = (unsigned long long)p;
    unsigned lo = __builtin_amdgcn_readfirstlane((unsigned)u);
    unsigned hi = __builtin_amdgcn_readfirstlane((unsigned)(u >> 32));
    return (const float*)(((unsigned long long)hi << 32) | lo);
}

// raw barrier: LDS writes visible, global loads stay in flight (no vmcnt drain)
#define LBAR() do {                                                  \
    asm volatile("s_waitcnt lgkmcnt(0)" ::: "memory");               \
    __builtin_amdgcn_sched_barrier(0);                               \
    __builtin_amdgcn_s_barrier();                                    \
    __builtin_amdgcn_sched_barrier(0);                               \
} while (0)

// one 16-col compute block: GEMM1 (4 MFMAs per ds_read_b128) + radial + GEMM2.
// Wave owns k [wave*64, +64) = 4 k-tiles; per jb-read all 4 hp chains advance.
#define CBODY(CB)                                                                  \
{                                                                                  \
    const int colb = (CB) * 16;                                                    \
    Frag2U gf;                                                                     \
    gf.u = *(const u32x2*)(gTP +                                                   \
           (((unsigned)(il * 128 + (colb + q * 4) * 2)) ^                          \
            (((unsigned)(il & 7)) << 3)));                                         \
    f32x4 hp0 = {0.f,0.f,0.f,0.f}, hp1 = {0.f,0.f,0.f,0.f};                        \
    f32x4 hp2 = {0.f,0.f,0.f,0.f}, hp3 = {0.f,0.f,0.f,0.f};                        \
    const unsigned rb = (unsigned)((colb + il) * 512);                             \
    _Pragma("unroll")                                                              \
    for (int jb = 0; jb < 8; ++jb) {                                               \
        FragU f0;                                                                  \
        f0.u = *(const u32x4*)((const char*)htP +                                  \
               ((rb + (unsigned)(jb * 64 + q * 16)) ^ sw));                        \
        hp0 = __builtin_amdgcn_mfma_f32_16x16x32_bf16(f0.b, wf[0][jb].b, hp0, 0, 0, 0); \
        hp1 = __builtin_amdgcn_mfma_f32_16x16x32_bf16(f0.b, wf[1][jb].b, hp1, 0, 0, 0); \
        hp2 = __builtin_amdgcn_mfma_f32_16x16x32_bf16(f0.b, wf[2][jb].b, hp2, 0, 0, 0); \
        hp3 = __builtin_amdgcn_mfma_f32_16x16x32_bf16(f0.b, wf[3][jb].b, hp3, 0, 0, 0); \
    }                                                                              \
    f32x4 d4 = *(const f32x4*)(dtP + colb + q * 4);                                \
    f32x4 i4 = *(const f32x4*)(dtP + 64 + colb + q * 4);                           \
    {                                                                              \
        Frag2U a;                                                                  \
        float m0 = __sinf(fkb * d4[0]) * i4[0] * hp0[0];                           \
        float m1 = __sinf(fkb * d4[1]) * i4[1] * hp0[1];                           \
        float m2 = __sinf(fkb * d4[2]) * i4[2] * hp0[2];                           \
        float m3 = __sinf(fkb * d4[3]) * i4[3] * hp0[3];                           \
        a.u[0] = pk2(m0, m1); a.u[1] = pk2(m2, m3);                                \
        acc0 = __builtin_amdgcn_mfma_f32_16x16x16bf16_1k(a.s, gf.s, acc0, 0, 0, 0);\
        m0 = __sinf((fkb + 16.f) * d4[0]) * i4[0] * hp1[0];                        \
        m1 = __sinf((fkb + 16.f) * d4[1]) * i4[1] * hp1[1];                        \
        m2 = __sinf((fkb + 16.f) * d4[2]) * i4[2] * hp1[2];                        \
        m3 = __sinf((fkb + 16.f) * d4[3]) * i4[3] * hp1[3];                        \
        a.u[0] = pk2(m0, m1); a.u[1] = pk2(m2, m3);                                \
        acc1 = __builtin_amdgcn_mfma_f32_16x16x16bf16_1k(a.s, gf.s, acc1, 0, 0, 0);\
        m0 = __sinf((fkb + 32.f) * d4[0]) * i4[0] * hp2[0];                        \
        m1 = __sinf((fkb + 32.f) * d4[1]) * i4[1] * hp2[1];                        \
        m2 = __sinf((fkb + 32.f) * d4[2]) * i4[2] * hp2[2];                        \
        m3 = __sinf((fkb + 32.f) * d4[3]) * i4[3] * hp2[3];                        \
        a.u[0] = pk2(m0, m1); a.u[1] = pk2(m2, m3);                                \
        acc2 = __builtin_amdgcn_mfma_f32_16x16x16bf16_1k(a.s, gf.s, acc2, 0, 0, 0);\
        m0 = __sinf((fkb + 48.f) * d4[0]) * i4[0] * hp3[0];                        \
        m1 = __sinf((fkb + 48.f) * d4[1]) * i4[1] * hp3[1];                        \
        m2 = __sinf((fkb + 48.f) * d4[2]) * i4[2] * hp3[2];                        \
        m3 = __sinf((fkb + 48.f) * d4[3]) * i4[3] * hp3[3];                        \
        a.u[0] = pk2(m0, m1); a.u[1] = pk2(m2, m3);                                \
        acc3 = __builtin_amdgcn_mfma_f32_16x16x16bf16_1k(a.s, gf.s, acc3, 0, 0, 0);\
    }                                                                              \
}

// issue 16-row chunk Q of next tile (col c) into DST[16]
#define CHUNK16_ISSUE(DST, Q)                                                      \
    if (hasNext) {                                                                 \
        _Pragma("unroll")                                                          \
        for (int j = 0; j < 16; ++j)                                               \
            DST[j] = hwb[(size_t)((Q) * 16 + j) * NNB + baseN + c];                \
    }

// pack 16-row chunk Q into htN: rows wave*64 + Q*16 .. +16 at col c (2x b128)
#define CHUNK16_PACK(SRC, Q)                                                       \
    if (hasNext) {                                                                 \
        u32x4 w0, w1;                                                              \
        w0[0] = pk2(SRC[0],  SRC[1]);  w0[1] = pk2(SRC[2],  SRC[3]);               \
        w0[2] = pk2(SRC[4],  SRC[5]);  w0[3] = pk2(SRC[6],  SRC[7]);               \
        w1[0] = pk2(SRC[8],  SRC[9]);  w1[1] = pk2(SRC[10], SRC[11]);              \
        w1[2] = pk2(SRC[12], SRC[13]); w1[3] = pk2(SRC[14], SRC[15]);              \
        const unsigned boff = (unsigned)(c * 512 + wave * 128 + (Q) * 32);         \
        *(u32x4*)((char*)htN + ((boff)      ^ swc)) = w0;                          \
        *(u32x4*)((char*)htN + ((boff + 16) ^ swc)) = w1;                          \
    }

// K1: 256 threads = 4 waves, 2 blocks/CU. __launch_bounds__(256,2) -> predicted
// 256-VGPR budget (rule: 131072/(threads*max(arg,2)); fits R1/R3/R9/R5-7 data).
// Wave owns k [wave*64,+64) (wf[4][8] = 128 VGPR resident; ds_read feeds 4 MFMAs).
// Staging: wave stages rows [wave*64,+64) at lane col; 16-row chunks, 2-deep
// ping-pong (32 f32 in flight/thread -> ~57 KB/CU outstanding, the queue-depth fix).
// ws layout: [block][entry = k*6 + m6]
__global__ __launch_bounds__(NTHREADS, 2) void create_As_k1(
        const float* __restrict__ h, const float* __restrict__ rp,
        const float* __restrict__ W, float* __restrict__ ws)
{
    __shared__ unsigned short htile[2][BN * NCH];        // 2 x 32 KB [col][j], ^((col&7)<<4)
    __shared__ unsigned short gT[2][16 * BN];            // 2 x 2 KB [de][col], ^((de&7)<<3)
    __shared__ __align__(16) float dtab[2][2][BN];       // [p][{d,invd}][col]

    const int t    = threadIdx.x;
    const int wave = t >> 6;        // 0..3
    const int il   = t & 15;
    const int q    = (t >> 4) & 3;
    const int c    = t & 63;
    const int k0   = wave * 64;
    const unsigned sw  = ((unsigned)(il & 7)) << 4;
    const unsigned swc = ((unsigned)(c & 7)) << 4;
    const float fkb = (float)(k0 + il + 1);

    // zero gT (rows 6..15 must stay zero): 1024 u32, 256 threads x 4
    #pragma unroll
    for (int z = 0; z < 4; ++z) ((unsigned*)gT)[t + z * NTHREADS] = 0u;

    // W fragments: lane holds W[k0 + kt*16 + il][jb*32 + q*8 + e]  (128 VGPR resident)
    FragU wf[4][8];
    #pragma unroll
    for (int kt = 0; kt < 4; ++kt) {
        const float* wr = W + (size_t)(k0 + kt * 16 + il) * NCH + q * 8;
        #pragma unroll
        for (int jb = 0; jb < 8; ++jb) {
            f32x4 a = *(const f32x4*)(wr + jb * 32);
            f32x4 b = *(const f32x4*)(wr + jb * 32 + 4);
            wf[kt][jb].u[0] = pk2(a[0], a[1]);
            wf[kt][jb].u[1] = pk2(a[2], a[3]);
            wf[kt][jb].u[2] = pk2(b[0], b[1]);
            wf[kt][jb].u[3] = pk2(b[2], b[3]);
        }
    }

    f32x4 acc0 = {0.f,0.f,0.f,0.f};
    f32x4 acc1 = {0.f,0.f,0.f,0.f};
    f32x4 acc2 = {0.f,0.f,0.f,0.f};
    f32x4 acc3 = {0.f,0.f,0.f,0.f};

    // staging rows: wave stages rows [wave*64, +64) at its lane's col c
    const float* hwb = uni_ptr(h + (size_t)(wave * 64) * NNB);

    const int d0 = blockIdx.x;

    __syncthreads();   // gT zero-init visible before prologue writes

    // -------- prologue: stage tile d0 into buf 0; geometry d0 (t<64) --------
    {
        const unsigned base = (unsigned)(d0 * BN);
        #pragma unroll
        for (int qq = 0; qq < 4; ++qq) {
            float hv[16];
            #pragma unroll
            for (int j = 0; j < 16; ++j)
                hv[j] = hwb[(size_t)(qq * 16 + j) * NNB + base + c];
            u32x4 w0, w1;
            w0[0] = pk2(hv[0],  hv[1]);  w0[1] = pk2(hv[2],  hv[3]);
            w0[2] = pk2(hv[4],  hv[5]);  w0[3] = pk2(hv[6],  hv[7]);
            w1[0] = pk2(hv[8],  hv[9]);  w1[1] = pk2(hv[10], hv[11]);
            w1[2] = pk2(hv[12], hv[13]); w1[3] = pk2(hv[14], hv[15]);
            const unsigned boff = (unsigned)(c * 512 + wave * 128 + qq * 32);
            *(u32x4*)((char*)htile[0] + ((boff)      ^ swc)) = w0;
            *(u32x4*)((char*)htile[0] + ((boff + 16) ^ swc)) = w1;
        }
        if (t < 64) {
            const unsigned ii = base + (unsigned)c;
            float gx = rp[ii], gy = rp[(size_t)NNB + ii], gz = rp[2 * (size_t)NNB + ii];
            float dd = sqrtf(gx * gx + gy * gy + gz * gz);
            float iv = 1.0f / dd;
            dtab[0][0][c] = dd; dtab[0][1][c] = iv;
            float i2 = iv * iv;
            float gg[6] = { gx * gx * i2, gx * gy * i2, gx * gz * i2,
                            gy * gy * i2, gy * gz * i2, gz * gz * i2 };
            #pragma unroll
            for (int de = 0; de < 6; ++de) {
                unsigned off = ((unsigned)(de * 128 + c * 2)) ^ (((unsigned)de) << 3);
                *(unsigned short*)((char*)gT[0] + off) =
                    (unsigned short)(pk2(gg[de], 0.f) & 0xffffu);
            }
        }
    }
    LBAR();

    #pragma unroll 1
    for (int it = 0; it < ITPB; ++it) {
        const int P = it & 1;
        const unsigned short* htP = htile[P];
        unsigned short*       htN = htile[P ^ 1];
        const char*  gTP = (const char*)gT[P];
        const float* dtP = &dtab[P][0][0];
        const bool hasNext = (it + 1 < ITPB);
        const unsigned baseN = (unsigned)((d0 + (it + 1) * NB) * BN);

        // geometry rp for next tile: t<64 only, issued early, consumed at end
        float gx = 0.f, gy = 0.f, gz = 0.f;
        if (hasNext && t < 64) {
            const unsigned ii = baseN + (unsigned)c;
            gx = rp[ii]; gy = rp[(size_t)NNB + ii]; gz = rp[2 * (size_t)NNB + ii];
        }

        float hA[16], hB[16];
        CHUNK16_ISSUE(hA, 0)
        CHUNK16_ISSUE(hB, 1)          // 32 loads in flight entering compute
        __builtin_amdgcn_sched_barrier(0);
        CBODY(0)
        __builtin_amdgcn_sched_barrier(0);
        CHUNK16_PACK(hA, 0) CHUNK16_ISSUE(hA, 2)
        __builtin_amdgcn_sched_barrier(0);
        CBODY(1)
        __builtin_amdgcn_sched_barrier(0);
        CHUNK16_PACK(hB, 1) CHUNK16_ISSUE(hB, 3)
        __builtin_amdgcn_sched_barrier(0);
        CBODY(2)
        __builtin_amdgcn_sched_barrier(0);
        CHUNK16_PACK(hA, 2)
        __builtin_amdgcn_sched_barrier(0);
        CBODY(3)
        __builtin_amdgcn_sched_barrier(0);
        CHUNK16_PACK(hB, 3)
        if (hasNext && t < 64) {   // geometry for next tile into buf P^1
            float dd = sqrtf(gx * gx + gy * gy + gz * gz);
            float iv = 1.0f / dd;
            dtab[P ^ 1][0][c] = dd; dtab[P ^ 1][1][c] = iv;
            float i2 = iv * iv;
            float gg[6] = { gx * gx * i2, gx * gy * i2, gx * gz * i2,
                            gy * gy * i2, gy * gz * i2, gz * gz * i2 };
            #pragma unroll
            for (int de = 0; de < 6; ++de) {
                unsigned off = ((unsigned)(de * 128 + c * 2)) ^ (((unsigned)de) << 3);
                *(unsigned short*)((char*)gT[P ^ 1] + off) =
                    (unsigned short)(pk2(gg[de], 0.f) & 0xffffu);
            }
        }
        LBAR();
    }

    // ---- store: lane holds A[k = k0 + kt*16 + q*4 + r][de = il] ----
    if (il < 6) {
        float* dst = ws + (size_t)blockIdx.x * NENT;
        #pragma unroll
        for (int r = 0; r < 4; ++r) {
            dst[(k0 +      q * 4 + r) * 6 + il] = acc0[r];
            dst[(k0 + 16 + q * 4 + r) * 6 + il] = acc1[r];
            dst[(k0 + 32 + q * 4 + r) * 6 + il] = acc2[r];
            dst[(k0 + 48 + q * 4 + r) * 6 + il] = acc3[r];
        }
    }
}

// K2: 24 blocks x 512. Block eb owns entries [eb*64, +64); coalesced rows; LDS reduce.
__global__ void create_As_k2(const float* __restrict__ ws, float* __restrict__ out)
{
    __shared__ float red[8][64];
    const int eb = blockIdx.x;
    const int w  = threadIdx.x >> 6;
    const int l  = threadIdx.x & 63;
    float s = 0.f;
    #pragma unroll 4
    for (int b = w; b < NB; b += 8)
        s += ws[(size_t)b * NENT + (unsigned)(eb * 64 + l)];
    red[w][l] = s;
    __syncthreads();
    if (w == 0) {
        float v = red[0][l] + red[1][l] + red[2][l] + red[3][l]
                + red[4][l] + red[5][l] + red[6][l] + red[7][l];
        const int e  = eb * 64 + l;
        const int k  = e / 6;
        const int m6 = e - k * 6;
        const int d  = (m6 < 3) ? 0 : ((m6 < 5) ? 1 : 2);
        const int e2 = (m6 < 3) ? m6 : ((m6 < 5) ? (m6 - 2) : 2);
        out[k * 9 + d * 3 + e2] = v;
        if (d != e2) out[k * 9 + e2 * 3 + d] = v;
    }
}

extern "C" void kernel_launch(void* const* d_in, const int* in_sizes, int n_in,
                              void* d_out, int out_size, void* d_ws, size_t ws_size,
                              hipStream_t stream)
{
    const float* h  = (const float*)d_in[0];
    const float* rp = (const float*)d_in[1];
    const float* W  = (const float*)d_in[2];
    float* out = (float*)d_out;
    float* ws  = (float*)d_ws;

    hipLaunchKernelGGL(create_As_k1, dim3(NB), dim3(NTHREADS), 0, stream, h, rp, W, ws);
    hipLaunchKernelGGL(create_As_k2, dim3(NENT / 64), dim3(512), 0, stream, ws, out);
}